// Round 8
// baseline (5008.187 us; speedup 1.0000x reference)
//
#include <hip/hip_runtime.h>
#include <hip/hip_bf16.h>
#include <stdint.h>

#define B_   64
#define T_   1024
#define D_   300
#define H_   512
#define G4H  2048
#define KP   320   // K padded to multiple of 32 for the x-proj GEMM

typedef __attribute__((ext_vector_type(8))) short short8;   // 8 x bf16 (4 VGPRs)
typedef __attribute__((ext_vector_type(4))) float f32x4;
typedef unsigned long long ull;

__device__ __forceinline__ unsigned short f2bf(float v) {
    __hip_bfloat16 h = __float2bfloat16(v);
    return *reinterpret_cast<unsigned short*>(&h);
}
__device__ __forceinline__ float bf2f(unsigned u) {      // low 16 bits = bf16
    return __uint_as_float(u << 16);
}
__device__ __forceinline__ float sigm(float x) { return 1.f / (1.f + __expf(-x)); }
__device__ __forceinline__ float tanhfast(float x) {
    float e = __expf(2.f * x);            // inf-safe: x>>0 -> 1, x<<0 -> -1
    return 1.f - 2.f / (e + 1.f);
}

// LDS-only barrier: does NOT drain vmcnt (unlike __syncthreads, which emits
// s_waitcnt vmcnt(0) before s_barrier). HW-validated rounds 2/4/6/7.
__device__ __forceinline__ void bar_lds() {
    asm volatile("s_waitcnt lgkmcnt(0)" ::: "memory");
    __builtin_amdgcn_s_barrier();
    asm volatile("" ::: "memory");
}

#define ASYNC16(g, l)                                                        \
    __builtin_amdgcn_global_load_lds(                                        \
        (const __attribute__((address_space(1))) void*)(g),                  \
        (__attribute__((address_space(3))) void*)(l), 16, 0, 0)

// ---------------------------------------------------------------------------
// Kernel 1: essays fp32 [65536][300] -> bf16 [65536][320] (zero-padded K)
// ---------------------------------------------------------------------------
__global__ void cvt_essays(const float* __restrict__ es, unsigned short* __restrict__ Ab) {
    unsigned i = blockIdx.x * 256u + threadIdx.x;       // exactly 65536*320 threads
    unsigned row = i / KP;
    unsigned col = i - row * KP;
    float v = (col < D_) ? es[(size_t)row * D_ + col] : 0.f;
    Ab[i] = f2bf(v);
}

// ---------------------------------------------------------------------------
// Kernel 2: Wx transpose+pad -> bf16 WxT[2048][320]
// ---------------------------------------------------------------------------
__global__ void cvt_misc(const float* __restrict__ Wl, unsigned short* __restrict__ Bt) {
    unsigned i = blockIdx.x * 256u + threadIdx.x;       // exactly 2048*320 threads
    unsigned n = i / KP, k = i - n * KP;
    float v = (k < D_) ? Wl[(size_t)k * G4H + n] : 0.f;   // Wx rows 0..299
    Bt[i] = f2bf(v);
}

// ---------------------------------------------------------------------------
// Kernel 2b: Wh transpose -> bf16 WhTg[2048][512] (coalesced block staging)
// ---------------------------------------------------------------------------
__global__ void cvt_wh(const float* __restrict__ Wl, unsigned short* __restrict__ WhTg) {
    unsigned i = blockIdx.x * 256u + threadIdx.x;       // 2048*512 threads
    unsigned gc = i & 2047u, k = i >> 11;
    WhTg[(size_t)gc * 512 + k] = f2bf(Wl[(size_t)(300 + k) * G4H + gc]);
}

// ---------------------------------------------------------------------------
// Kernel 2c: init hfp data region (don't care) + FLAGS region (must be 0 —
// flags gate freshness; pre-LSTM garbage there would fake readiness).
// Covers 65536 data dwords + 512 flag dwords = 66048 = 258 blocks x 256.
// Must run AFTER gemm_xp (region overlaps Ab).
// ---------------------------------------------------------------------------
__global__ void init_hfp(unsigned* __restrict__ hfp) {
    hfp[blockIdx.x * 256u + threadIdx.x] = 0u;
}

// ---------------------------------------------------------------------------
// Kernel 3: x_proj GEMM -> xpr in recurrence layout (round-0 layout):
//   xpr[((t*4+g)*32+slice)*1024 + b*64 + gate*16 + jj]   (bf16, bias added)
// ---------------------------------------------------------------------------
__global__ __launch_bounds__(256) void gemm_xp(
    const unsigned short* __restrict__ Ab,   // [65536][320] bf16
    const unsigned short* __restrict__ Bt,   // [2048][320]  bf16 (WxT)
    const float* __restrict__ bias,          // [2048]
    unsigned short* __restrict__ xpr)        // [65536*2048] bf16, permuted
{
    __shared__ __align__(16) unsigned short Al[128 * 32];
    __shared__ __align__(16) unsigned short Bl[128 * 32];
    const int tid = threadIdx.x;
    const int w = tid >> 6, lane = tid & 63;
    const int ln = lane & 15, q = lane >> 4;
    const int bx = blockIdx.x;
    const int m0 = (bx >> 4) * 128;          // consecutive blocks share the A tile
    const int n0 = (bx & 15) * 128;
    const int wr = w >> 1, wc = w & 1;

    f32x4 acc[4][4];
#pragma unroll
    for (int i = 0; i < 4; i++)
#pragma unroll
        for (int j = 0; j < 4; j++) acc[i][j] = (f32x4){0.f, 0.f, 0.f, 0.f};

    for (int k0 = 0; k0 < KP; k0 += 32) {
#pragma unroll
        for (int it = 0; it < 2; ++it) {
            int s = it * 4 + w;              // wave-uniform segment id
            int c = s * 64 + lane;           // 16B chunk id, 0..511
            int r = c >> 2;                  // tile row 0..127
            int ko = (c & 3) * 8;            // k offset in elements
            ASYNC16(Ab + (size_t)(m0 + r) * KP + k0 + ko, &Al[s * 512]);
            ASYNC16(Bt + (size_t)(n0 + r) * KP + k0 + ko, &Bl[s * 512]);
        }
        __syncthreads();
        short8 af[4], bf[4];
#pragma unroll
        for (int mt = 0; mt < 4; ++mt)
            af[mt] = *(const short8*)&Al[(wr * 64 + mt * 16 + ln) * 32 + q * 8];
#pragma unroll
        for (int nt = 0; nt < 4; ++nt)
            bf[nt] = *(const short8*)&Bl[(wc * 64 + nt * 16 + ln) * 32 + q * 8];
#pragma unroll
        for (int mt = 0; mt < 4; ++mt)
#pragma unroll
            for (int nt = 0; nt < 4; ++nt)
                acc[mt][nt] = __builtin_amdgcn_mfma_f32_16x16x32_bf16(af[mt], bf[nt], acc[mt][nt], 0, 0, 0);
        __syncthreads();
    }
#pragma unroll
    for (int mt = 0; mt < 4; ++mt) {
#pragma unroll
        for (int nt = 0; nt < 4; ++nt) {
            int col = n0 + wc * 64 + nt * 16 + ln;
            int gate = col >> 9, r9 = col & 511;
            int slice = r9 >> 4, jj = r9 & 15;
            float bb = bias[col];
#pragma unroll
            for (int r = 0; r < 4; ++r) {
                int row = m0 + wr * 64 + mt * 16 + q * 4 + r;   // C/D: col=lane&15, row=quad*4+reg
                int t = row & 1023, bglob = row >> 10;
                int g = bglob >> 4, bloc = bglob & 15;
                size_t idx = ((((size_t)t * 4 + g) * 32 + slice) * 16 + bloc) * 64
                             + gate * 16 + jj;
                xpr[idx] = f2bf(acc[mt][nt][r] + bb);
            }
        }
    }
}

// ---------------------------------------------------------------------------
// Kernel 4: persistent LSTM recurrence — round-7 structure with the exchange
// protocol swapped from data-as-flag polling to a PER-WAVE FLAG protocol.
// Round-7 diagnosis: the all-thread tag-retry polling flood (~25 MB/step
// device-wide, re-issued every ~600cy) saturates the fabric/coherence point
// and inflates store-visibility to ~2.5us — the system self-throttles.
// New protocol per step:
//   PRODUCER: coalesced h stores (raw fp32) -> s_waitcnt vmcnt(0) per wave
//     (data at coherence point) -> lane 0 stores monotonic flag t+1 into
//     flags[g][slice][wave]. No extra barrier (flags are per-wave).
//   CONSUMER: thread tid's 16 chunks come from exactly one producer block
//     (slice = tid>>3, pair = tid), so it spins on that block's 4 wave-flags
//     (two 8B broadcast loads; 8 threads share each line) until all >= t,
//     then issues its 16 data loads ONCE. No data retry ever.
// Freshness: flag>=t  =>  producer's h(t) (parity buf (t&1)) was drained to
// the coherence point before the flag was stored; skew<=1 keeps the two
// parity buffers disjoint; flags are monotonic so stale acceptance is
// impossible; init_hfp zeroes flags.
// Self-slice short-circuit + bar_lds + coalesced 64B-sector stores retained.
// ---------------------------------------------------------------------------
__global__ __launch_bounds__(256, 1) void lstm_rec(
    const unsigned short* __restrict__ WhTg, // [2048][512] bf16 (pre-transposed Wh)
    const unsigned short* __restrict__ xpr,  // permuted x_proj (see gemm_xp)
    unsigned* __restrict__ hfp,              // [2][64][512] fp32 h
    unsigned* __restrict__ flags,            // [4][32][4] monotonic step flags
    float* __restrict__ hmean)               // [64][512] fp32
{
    __shared__ __align__(16) unsigned short WhT[64 * 520];   // [col][k], pad 520
    __shared__ __align__(16) unsigned short hl[16 * 520];    // [b][k], pad 520
    __shared__ float gbuf[4][16][17];                        // [gate][b][j], pad 17

    const int tid = threadIdx.x;
    const int bid = blockIdx.x;
    const int g     = bid >> 5;        // batch group 0..3
    const int slice = bid & 31;        // j-slice 0..31
    const int j0    = slice * 16;
    const int bg    = g * 16;
    const int wv = tid >> 6, lane = tid & 63, ln = lane & 15, q = lane >> 4;
    const bool skip = (tid >> 3) == slice;   // own chunks: local via LDS

    // one-time: stage this block's 64 Wh columns (gate*16+j) from WhTg, coalesced
    for (int ch = tid; ch < 64 * 64; ch += 256) {            // 16B chunks
        int c = ch >> 6, off = (ch & 63) * 8;
        int gc = (c >> 4) * 512 + j0 + (c & 15);
        *(uint4*)&WhT[c * 520 + off] = *(const uint4*)&WhTg[(size_t)gc * 512 + off];
    }

    const int b = tid >> 4;            // local batch row 0..15
    const int j = tid & 15;            // local j
    const int rowoff = (bg + b) * 512;

    // h(0) = 0: zero the staged-h LDS
    {
        ull* hl8 = (ull*)hl;
#pragma unroll
        for (int i = 0; i < 16; ++i) {
            int c = tid + (i << 8);                          // ull chunk 0..4095
            int row = c >> 8, pair = c & 255;                // 256 ull per row
            hl8[(row * 1040 + pair * 8) >> 3] = 0ull;        // byte addr /8
        }
    }
    __syncthreads();                   // one-time full barrier (off the loop)

    float c_st = 0.f, hsum = 0.f;
    const unsigned short* xblk0 = xpr + ((size_t)g * 32 + slice) * 1024 + b * 64 + j;
    unsigned short xc0 = xblk0[0], xc1 = xblk0[16], xc2 = xblk0[32], xc3 = xblk0[48];
    unsigned short xn0 = xc0, xn1 = xc1, xn2 = xc2, xn3 = xc3;

    // this thread's producer-block flag line (4 wave-flags, 16B)
    const ull* fp = (const ull*)(flags + (g * 32 + (tid >> 3)) * 4);

    for (int t = 0; t < T_; ++t) {
        // issue xp(t+1) prefetch FIRST: latency hides under the flag wait
        if (t + 1 < T_) {
            const unsigned short* xr = xblk0 + (size_t)(t + 1) * 131072;  // 4*32*1024
            xn0 = xr[0]; xn1 = xr[16]; xn2 = xr[32]; xn3 = xr[48];
        }
        if (t > 0 && !skip) {
            // ---- wait for producer block's 4 wave-flags to reach step t
            const unsigned wantf = (unsigned)t;
            while (true) {
                ull f01 = __hip_atomic_load(fp,     __ATOMIC_RELAXED, __HIP_MEMORY_SCOPE_AGENT);
                ull f23 = __hip_atomic_load(fp + 1, __ATOMIC_RELAXED, __HIP_MEMORY_SCOPE_AGENT);
                if ((unsigned)f01 >= wantf && (unsigned)(f01 >> 32) >= wantf &&
                    (unsigned)f23 >= wantf && (unsigned)(f23 >> 32) >= wantf) break;
            }
            // ---- single-shot data load (16 coalesced 8B agent loads), decode
            const ull* src = (const ull*)(hfp + (size_t)(t & 1) * 32768 + bg * 512);
            ull v[16];
#pragma unroll
            for (int i = 0; i < 16; ++i)
                v[i] = __hip_atomic_load(src + tid + (i << 8),
                                         __ATOMIC_RELAXED, __HIP_MEMORY_SCOPE_AGENT);
#pragma unroll
            for (int i = 0; i < 16; ++i) {
                int c = tid + (i << 8);
                int row = c >> 8, pair = c & 255;
                unsigned u = (unsigned)f2bf(__uint_as_float((unsigned)v[i]))
                           | ((unsigned)f2bf(__uint_as_float((unsigned)(v[i] >> 32))) << 16);
                *(unsigned*)((char*)hl + row * 1040 + pair * 4) = u;
            }
        }
        bar_lds();                                           // bar1: RAW on hl

        // wave wv computes gate wv: 16(batch) x 16(j), K=512
        f32x4 acc = (f32x4){0.f, 0.f, 0.f, 0.f};
#pragma unroll
        for (int kk = 0; kk < 16; ++kk) {
            short8 av = *(const short8*)&hl[ln * 520 + kk * 32 + q * 8];
            short8 bv = *(const short8*)&WhT[(wv * 16 + ln) * 520 + kk * 32 + q * 8];
            acc = __builtin_amdgcn_mfma_f32_16x16x32_bf16(av, bv, acc, 0, 0, 0);
        }
#pragma unroll
        for (int r = 0; r < 4; ++r)
            gbuf[wv][q * 4 + r][ln] = acc[r];                // C/D: col=lane&15, row=quad*4+reg
        bar_lds();                                           // bar2: gbuf RAW + hl WAR

        // elementwise: thread (b, j)
        float ai  = gbuf[0][b][j] + bf2f((unsigned)xc0);
        float aj  = gbuf[1][b][j] + bf2f((unsigned)xc1);
        float af_ = gbuf[2][b][j] + bf2f((unsigned)xc2);
        float ao  = gbuf[3][b][j] + bf2f((unsigned)xc3);
        float si = sigm(ai), tj = tanhfast(aj);
        float sf = sigm(af_ + 1.0f), so = sigm(ao);
        c_st = c_st * sf + si * tj;
        float h = tanhfast(c_st) * so;
        hsum += h;
        xc0 = xn0; xc1 = xn1; xc2 = xn2; xc3 = xn3;

        // own h(t+1) -> LDS directly (hl region free after bar2)
        hl[b * 520 + j0 + j] = f2bf(h);

        // ---- publish h(t+1): coalesced stores -> per-wave drain -> wave flag
        __hip_atomic_store(hfp + (size_t)((t + 1) & 1) * 32768 + rowoff + j0 + j,
                           __float_as_uint(h), __ATOMIC_RELAXED, __HIP_MEMORY_SCOPE_AGENT);
        asm volatile("s_waitcnt vmcnt(0)" ::: "memory");     // data at coherence point
        if ((tid & 63) == 0)
            __hip_atomic_store(flags + (g * 32 + slice) * 4 + wv, (unsigned)(t + 1),
                               __ATOMIC_RELAXED, __HIP_MEMORY_SCOPE_AGENT);
    }
    hmean[(size_t)rowoff + j0 + j] = hsum * (1.f / 1024.f);
}

// ---------------------------------------------------------------------------
// Kernel 5: preds = sigmoid(hmean @ W_dense + b_dense), one wave per batch row
// ---------------------------------------------------------------------------
__global__ void dense_out(const float* __restrict__ hmean, const float* __restrict__ Wd,
                          const float* __restrict__ bd, float* __restrict__ out) {
    int bb = blockIdx.x;
    int lane = threadIdx.x;
    float p = 0.f;
    for (int e = lane; e < H_; e += 64) p += hmean[(size_t)bb * H_ + e] * Wd[e];
#pragma unroll
    for (int off = 32; off; off >>= 1) p += __shfl_down(p, off);
    if (lane == 0) out[bb] = 1.f / (1.f + __expf(-(p + bd[0])));
}

// ---------------------------------------------------------------------------
extern "C" void kernel_launch(void* const* d_in, const int* in_sizes, int n_in,
                              void* d_out, int out_size, void* d_ws, size_t ws_size,
                              hipStream_t stream) {
    const float* essays  = (const float*)d_in[0];
    const float* W_lstm  = (const float*)d_in[1];
    const float* b_lstm  = (const float*)d_in[2];
    const float* W_dense = (const float*)d_in[3];
    const float* b_dense = (const float*)d_in[4];
    float* out = (float*)d_out;

    char* ws = (char*)d_ws;
    unsigned short* xp   = (unsigned short*)(ws);                   // 256 MB (permuted)
    unsigned short* Ab   = (unsigned short*)(ws + 268435456ull);    // 40 MB (dead after gemm_xp)
    unsigned short* Bt   = (unsigned short*)(ws + 310378496ull);    // 1.25 MB
    unsigned short* WhTg = (unsigned short*)(ws + 311689216ull);    // 2 MB
    // hfp/flags/hm overlap the Ab region (Ab dead once gemm_xp completes)
    unsigned*       hfp  = (unsigned*)(ws + 268435456ull);          // 256 KB data
    unsigned*       flg  = (unsigned*)(ws + 268435456ull + 262144ull);   // 2 KB flags
    float*          hm   = (float*)(ws + 268435456ull + 264192ull); // 128 KB

    hipLaunchKernelGGL(cvt_essays, dim3(81920), dim3(256), 0, stream, essays, Ab);
    hipLaunchKernelGGL(cvt_misc,   dim3(2560),  dim3(256), 0, stream, W_lstm, Bt);
    hipLaunchKernelGGL(cvt_wh,     dim3(4096),  dim3(256), 0, stream, W_lstm, WhTg);
    hipLaunchKernelGGL(gemm_xp,    dim3(8192),  dim3(256), 0, stream, Ab, Bt, b_lstm, xp);
    hipLaunchKernelGGL(init_hfp,   dim3(258),   dim3(256), 0, stream, hfp);
    hipLaunchKernelGGL(lstm_rec,   dim3(128),   dim3(256), 0, stream, WhTg, xp, hfp, flg, hm);
    hipLaunchKernelGGL(dense_out,  dim3(64),    dim3(64),  0, stream, hm, W_dense, b_dense, out);
}